// Round 2
// baseline (110.681 us; speedup 1.0000x reference)
//
#include <hip/hip_runtime.h>
#include <math.h>

// DILATE / soft-DTW — round 14: BAND-SERIAL single-wave blocks (no barriers).
// r13 post-mortem: 2-problem ILP per wave worked per-block (1.74x) but halved
// block-level TLP (1 block/CU) and kept the barrier-synced 3-wave pipeline ->
// net regression. Root cause both rounds: the cross-wave pipeline costs ~300
// cyc/step (barrier drain + phase skew + window latency) vs ~45 cyc chain.
// r14: ONE wave per problem processes the 3 row-bands SEQUENTIALLY, reusing
// the identical ring/DPP/injection machinery. Producer and consumer of the
// ring are now the same wave => no barriers at all, no pipeline fill/drain.
// 640 wall-steps (vs 352) but each at issue-bound ~60-70 cyc (vs ~300).
//  - 512 blocks x 64 threads (2 blocks/CU, 1 wave each).
//  - Single ring bRG[RSZ] float2: band w writes slot d at step d; band w+1
//    reads slot d (prefetched one chunk ahead) strictly before that write.
//    The only read-before-write overlaps are window slots rgx[0..1], which
//    are dead except at a band's first chunk (where no overlap exists).
//  - Double-buffered REGISTER windows: next chunk's 9 ring b128 + 4 P b128
//    issue before current chunk's 16-step compute (latency hidden, no
//    aliasing within a band: write range [16c+2,16c+17] vs prefetch range
//    [16c+16,16c+33] overlaps only at the dead slots).
//  - Per-cell inputs and op order bit-identical to r12 -> absmax 0.0.
// Kept: C2-domain carry (GLN2*C2==1 exact), subtract-form exp args (r5),
// DPP old-injection, unwritten-slot==(BIGC2,0) border semantics, garbage
// j<=0 / j>160 cells self-contained (publish ~1e12 border-like values).

#define NN     160
#define BC_TOT 512
#define B_SZ   64
#define C_SZ   8
#define BIGC2  1e12f              // border sentinel in C2 domain
#define SC2    12.01122405f       // sqrt(C2), C2 = 144.269504089
#define GLN2   0.0069314718056f   // gamma*ln2 == 1/C2
#define KPH    16
#define RSZ    328                // ring slots (reads up to 321)

__device__ __forceinline__ float fexp2(float x) {
#if __has_builtin(__builtin_amdgcn_exp2f)
    return __builtin_amdgcn_exp2f(x);
#else
    return exp2f(x);
#endif
}
__device__ __forceinline__ float flog2(float x) {
#if __has_builtin(__builtin_amdgcn_logf)
    return __builtin_amdgcn_logf(x);
#else
    return log2f(x);
#endif
}
__device__ __forceinline__ float frcp(float x) {
#if __has_builtin(__builtin_amdgcn_rcpf)
    return __builtin_amdgcn_rcpf(x);
#else
    return 1.0f / x;
#endif
}
// lane i <- lane i-1; lane 0 <- old (bound_ctrl=false). Standard scan idiom.
__device__ __forceinline__ float dpp_up1_inj(float old, float x) {
    int oi = __builtin_bit_cast(int, old);
    int xi = __builtin_bit_cast(int, x);
    return __builtin_bit_cast(float,
        __builtin_amdgcn_update_dpp(oi, xi, 0x138, 0xF, 0xF, false)); // wave_shr1
}
// LDS-only barrier (no vmcnt drain). 0xC07F = vmcnt(63) expcnt(7) lgkmcnt(0).
__device__ __forceinline__ void barrier_lds() {
    __asm__ __volatile__("" ::: "memory");
    __builtin_amdgcn_s_waitcnt(0xC07F);
    __builtin_amdgcn_s_barrier();
    __asm__ __volatile__("" ::: "memory");
}

// Load register window for chunk c_: ring slots [dlo-2, dlo+15] + P window.
#define LOAD_WIN(c_, rgx_, rgd_, pvv_) do {                                   \
    const int dlo_ = 2 + (c_) * KPH;                                          \
    if (w > 0) {                                                              \
        const float4* q_ = (const float4*)&bRG[dlo_ - 2];                     \
        _Pragma("unroll")                                                     \
        for (int x_ = 0; x_ < 9; ++x_) {                                      \
            const float4 v4_ = q_[x_];                                        \
            rgx_[2 * x_]     = v4_.x; rgd_[2 * x_]     = v4_.y;               \
            rgx_[2 * x_ + 1] = v4_.z; rgd_[2 * x_ + 1] = v4_.w;               \
        }                                                                     \
    } else {                                                                  \
        _Pragma("unroll")                                                     \
        for (int x_ = 0; x_ < 18; ++x_) { rgx_[x_] = BIGC2; rgd_[x_] = 0.0f; }\
        if ((c_) == 0) rgx_[0] = 0.0f;   /* R[0][0] = 0 seed at d=2 */        \
    }                                                                         \
    const int A_  = 192 - (64 * w + lane) + KPH * (c_);                       \
    const int sA_ = A_ & 3;                                                   \
    const float4* pq_ = (const float4*)&Pp[sA_][A_ - sA_];                    \
    _Pragma("unroll")                                                         \
    for (int x_ = 0; x_ < 4; ++x_) {                                          \
        const float4 p4_ = pq_[x_];                                           \
        pvv_[4 * x_]     = p4_.x; pvv_[4 * x_ + 1] = p4_.y;                   \
        pvv_[4 * x_ + 2] = p4_.z; pvv_[4 * x_ + 3] = p4_.w;                   \
    }                                                                         \
} while (0)

// 16 DP steps of chunk c_ using window regs. Op order identical to r12.
#define COMP_CHUNK(c_, rgx_, rgd_, pvv_) do {                                 \
    const int dlo_ = 2 + (c_) * KPH;                                          \
    if ((c_) == cLo) {   /* one-time boundary injection (first chunk) */      \
        u1 = isL0 ? rgx_[1] : BIGC2;  u2 = isL0 ? rgx_[0] : BIGC2;            \
        v1 = isL0 ? rgd_[1] : 0.0f;   v2 = isL0 ? rgd_[0] : 0.0f;             \
    }                                                                         \
    float djf_ = (float)(dlo_ - ti2);    /* j - i at u=0 */                   \
    _Pragma("unroll")                                                         \
    for (int u_ = 0; u_ < KPH; ++u_) {                                        \
        const int d_ = dlo_ + u_;                                             \
        const float mn = fminf(u2, fminf(u1, r1));                            \
        const float ed = fexp2(mn - u2);   /* SUBTRACT form (r5 rule) */      \
        const float ev = fexp2(mn - u1);                                      \
        const float eh = fexp2(mn - r1);                                      \
        const float ss = ed + ev + eh;     /* >= 1 */                         \
        const float rs = frcp(ss);                                            \
        const float dt = trS - pvv_[u_];                                      \
        const float rC = __builtin_fmaf(dt, dt, mn) - flog2(ss);              \
        const float nm = __builtin_fmaf(ed, v2,                               \
                         __builtin_fmaf(ev, v1, eh * s1));                    \
        const float rd = __builtin_fmaf(nm, rs, djf_ * djf_);                 \
        if (pub) { float2 pb; pb.x = rC; pb.y = rd; bRG[d_] = pb; }           \
        if (d_ == 2 * NN) {                                                   \
            if (w == 2 && lane == NN - 1 - 128) {  /* cell (160,160) */       \
                sdtw[k] = rC * GLN2;                                          \
                wlt[k]  = rd * (1.0f / (NN * NN));                            \
            }                                                                 \
        }                                                                     \
        u2 = u1; u1 = dpp_up1_inj(rgx_[u_ + 2], rC);  /* lane0 <- slot d */   \
        v2 = v1; v1 = dpp_up1_inj(rgd_[u_ + 2], rd);                          \
        r1 = rC; s1 = rd;                                                     \
        djf_ += 1.0f;                                                         \
    }                                                                         \
} while (0)

__global__ __launch_bounds__(64)
void dtw_fwd_kernel(const float* __restrict__ input,
                    const float* __restrict__ target,
                    float* __restrict__ sdtw,    // BC_TOT: R[N,N]
                    float* __restrict__ wlt)     // BC_TOT: Rdot[N,N]/N^2
{
    const int k    = blockIdx.x;
    const int lane = threadIdx.x;                // 0..63, one wave

    __shared__ __align__(16) float  Pp[4][520];  // replica s: Pp[s][y]=V(y+s)*SC2
    __shared__ __align__(16) float2 bRG[RSZ];    // ring: (rC2, rdot) @ slot=diag

    const float* tg = target + (size_t)k * NN;
    const float* pg = input  + (size_t)k * NN;
    // V(z) = P[z-192]*SC2 for z in [192,352), else 0
    for (int x = lane; x < 520; x += 64) {
        #pragma unroll
        for (int s = 0; s < 4; ++s) {
            const int v = x + s - 192;
            Pp[s][x] = ((unsigned)v < (unsigned)NN) ? pg[v] * SC2 : 0.0f;
        }
    }
    for (int x = lane; x < RSZ; x += 64) {
        float2 z; z.x = BIGC2; z.y = 0.0f;       // unwritten slot == true border
        bRG[x] = z;
    }
    const float tr0 = tg[lane] * SC2;            // rows 1..64
    const float tr1 = tg[64 + lane] * SC2;       // rows 65..128
    const float tr2 = (lane < NN - 128) ? tg[128 + lane] * SC2 : 0.0f; // 129..160
    barrier_lds();

    const bool isL0 = (lane == 0);

    for (int w = 0; w < 3; ++w) {                // SERIAL bands, same wave
        // cross-band LDS ordering fence (compiler-level; HW DS is in-order)
        __asm__ __volatile__("" ::: "memory");
        const int  cLo = 4 * w;                  // chunks [4w, min(19,4w+13)]
        const int  cHi = (4 * w + 13 < 19) ? 4 * w + 13 : 19;
        const bool pub = (lane == 63) && (w < 2);
        const float trS = (w == 0) ? tr0 : (w == 1) ? tr1 : tr2;
        const int  ti2 = 2 * (64 * w + lane + 1);   // 2*i

        // rolling state (C2 domain); borders reset per band
        float r1 = BIGC2, u1 = BIGC2, u2 = BIGC2;
        float s1 = 0.0f,  v1 = 0.0f,  v2 = 0.0f;

        float rgxA[18], rgdA[18], pvvA[16];
        float rgxB[18], rgdB[18], pvvB[16];

        LOAD_WIN(cLo, rgxA, rgdA, pvvA);
        for (int c = cLo; c <= cHi; c += 2) {    // even chunk counts: 14/14/12
            LOAD_WIN(c + 1, rgxB, rgdB, pvvB);   // prefetch under compute
            COMP_CHUNK(c, rgxA, rgdA, pvvA);
            if (c + 2 <= cHi) LOAD_WIN(c + 2, rgxA, rgdA, pvvA);
            COMP_CHUNK(c + 1, rgxB, rgdB, pvvB);
        }
    }
}

// final reduction: per-batch means + scalar loss. One wave (64 threads = B).
__global__ __launch_bounds__(64)
void finalize_kernel(const float* __restrict__ sdtw,
                     const float* __restrict__ wlt,
                     float* __restrict__ out)
{
    const int b = threadIdx.x;   // 0..63
    float ls = 0.0f, lt = 0.0f;
    #pragma unroll
    for (int c = 0; c < C_SZ; ++c) {
        ls += sdtw[b * C_SZ + c];
        lt += wlt[b * C_SZ + c];
    }
    ls *= (1.0f / C_SZ);
    lt *= (1.0f / C_SZ);
    out[1 + b]        = ls;
    out[1 + B_SZ + b] = lt;
    float v = 0.5f * ls + 0.5f * lt;
    #pragma unroll
    for (int o = 32; o > 0; o >>= 1) v += __shfl_down(v, o);
    if (b == 0) out[0] = v * (1.0f / B_SZ);
}

extern "C" void kernel_launch(void* const* d_in, const int* in_sizes, int n_in,
                              void* d_out, int out_size, void* d_ws, size_t ws_size,
                              hipStream_t stream) {
    const float* input  = (const float*)d_in[0];
    const float* target = (const float*)d_in[1];
    float* out = (float*)d_out;   // 129 floats

    float* sdtw = (float*)d_ws;                 // 512 floats
    float* wlt  = sdtw + BC_TOT;                // 512 floats

    dtw_fwd_kernel<<<BC_TOT, 64, 0, stream>>>(input, target, sdtw, wlt);
    finalize_kernel<<<1, 64, 0, stream>>>(sdtw, wlt, out);
}